// Round 15
// baseline (113.593 us; speedup 1.0000x reference)
//
#include <hip/hip_runtime.h>
#include <hip/hip_bf16.h>

typedef _Float16 half2v __attribute__((ext_vector_type(2)));
typedef _Float16 half8  __attribute__((ext_vector_type(8)));
typedef float    f32x4  __attribute__((ext_vector_type(4)));

constexpr int kHD  = 10;
constexpr int kP   = 6;
constexpr int kNE  = 5;
constexpr int kH   = 128;
constexpr int kHin = 64;
constexpr int kSeg = 70;    // 60 xh row-segments + 10 xf row-segments

// packed-weight layout in d_ws (half2 pairs) -- attn + edge phases
constexpr int WF2  = 0;     // 60  : Wf  [p][20]
constexpr int WH2  = 60;    // 60  : Wh  [p][20]
constexpr int WATT2= 120;   // 30  : Watt[p][10]
constexpr int WDP2 = 150;   // 500 : Wdp [e][10][20]
constexpr int NPAIR= 650;
// MFMA B-fragments at byte offset 8192 in d_ws: 6 parts x 2 k-chunks x 64
// lanes x 8 halfs = 6144 halfs (12288 B)
constexpr int kBOff = 8192;

__device__ __forceinline__ float sigm(float v) {
    return 1.0f / (1.0f + __expf(-v));
}
__device__ __forceinline__ half2v pk(float a, float b) {
    half2v h; h[0] = (_Float16)a; h[1] = (_Float16)b; return h;
}
__device__ __forceinline__ unsigned bc(half2v h) {
    union { half2v h; unsigned u; } x; x.h = h; return x.u;
}
__device__ __forceinline__ float dot2(half2v a, half2v b, float c) {
    return __builtin_amdgcn_fdot2(a, b, c, false);
}

__global__ __launch_bounds__(256)
void prepack_weights(const float* __restrict__ Wf,  const float* __restrict__ Wh,
                     const float* __restrict__ Watt, const float* __restrict__ Wdp,
                     half2v* __restrict__ out)
{
    const int i = blockIdx.x * 256 + threadIdx.x;
    if (i >= NPAIR) return;
    const float* src; int k;
    if      (i < WH2)   { src = Wf;   k = i; }
    else if (i < WATT2) { src = Wh;   k = i - WH2; }
    else if (i < WDP2)  { src = Watt; k = i - WATT2; }
    else                { src = Wdp;  k = i - WDP2; }
    out[i] = pk(src[2 * k], src[2 * k + 1]);
}

// B-fragment prepack for mfma_f32_16x16x32_f16: lane l supplies
// B[k = q*32 + (l>>4)*8 + e][col = l&15], zero outside (k<40, col<10).
__global__ __launch_bounds__(256)
void prepack_mfma_b(const float* __restrict__ Wup, _Float16* __restrict__ outB)
{
    const int t = blockIdx.x * 256 + threadIdx.x;
    if (t >= 6144) return;
    const int e = t & 7;
    const int l = (t >> 3) & 63;
    const int q = (t >> 9) & 1;
    const int p = t >> 10;
    const int k = q * 32 + (l >> 4) * 8 + e;
    const int col = l & 15;
    _Float16 v = (_Float16)0.0f;
    if (k < 40 && col < 10) v = (_Float16)Wup[(p * kHD + col) * 40 + k];
    outB[t] = v;
}

// R13 anchor + MFMA update: attn/edges per-lane fdot2 as before; the
// [64px x 40] x [40 x 10] update matmul per part runs on matrix cores from a
// wave-private LDS A-buffer (144B row stride; in-order wave LDS, no barrier).
__global__ __launch_bounds__(256, 2)
void Part_Graph_51539607552364_kernel(
    const float* __restrict__ xf,  const float* __restrict__ xh0,
    const float* __restrict__ xh1, const float* __restrict__ xp,
    const half2v* __restrict__ w2, const _Float16* __restrict__ wB,
    const float* __restrict__ bfb, const float* __restrict__ bhb,
    const float* __restrict__ batt,
    float* __restrict__ out_xp,
    float* __restrict__ out_att)
{
    __shared__ float stage[kSeg * kHin];                 // 17920 B
    __shared__ __align__(16) _Float16 Abuf[4][64 * 72];  // 36864 B (tot 54784)

    const int bid = blockIdx.x;
    const int n   = bid >> 6;
    const int R   = bid & 63;
    const int yA  = R * 2;

    const float scale = 63.0f / 127.0f;
    int ry0 = (int)((float)yA * scale);
    ry0 = ry0 > (kHin - 2) ? (kHin - 2) : ry0;

    const int wv   = threadIdx.x >> 6;
    const int lane = threadIdx.x & 63;

    // ---- cooperative staging (R13 verbatim) ----
    for (int s = wv; s < kSeg; s += 4) {
        const float* src;
        if (s < 60) {
            const int map = s / 30, rem = s % 30;
            const int ch = rem / 3, r3 = rem % 3;
            int srow = ry0 + r3;
            srow = srow > (kHin - 1) ? (kHin - 1) : srow;
            src = (map ? xh1 : xh0) +
                  ((size_t)(n * kHD + ch) * kHin + srow) * kHin;
        } else {
            const int ch = s - 60;
            src = xf + ((size_t)(n * kHD + ch) * kHin + R) * kHin;
        }
        stage[s * kHin + lane] = src[lane];
    }
    __syncthreads();

    const int ly = threadIdx.x >> 7;
    const int xc = threadIdx.x & (kH - 1);
    const int yc = yA + ly;

    // ---- bilinear coords ----
    const float py = (float)yc * scale;
    int y0 = (int)py; y0 = y0 > (kHin - 2) ? (kHin - 2) : y0;
    const float fy = py - (float)y0;
    const int d0 = y0 - ry0;
    const float pxf_ = (float)xc * scale;
    int x0 = (int)pxf_; x0 = x0 > (kHin - 2) ? (kHin - 2) : x0;
    const float fx = pxf_ - (float)x0;
    const float w00 = (1.0f - fy) * (1.0f - fx);
    const float w01 = (1.0f - fy) * fx;
    const float w10 = fy * (1.0f - fx);
    const float w11 = fy * fx;

    // ---- windows from LDS -> packed half2 ----
    half2v xh0v2[5], xh1v2[5], xfv2[5];
    const int sx = xc >> 1;
    #pragma unroll
    for (int j = 0; j < 5; ++j) {
        float v[2], u[2], f[2];
        #pragma unroll
        for (int t = 0; t < 2; ++t) {
            const int c = 2 * j + t;
            const float* r0 = &stage[(c * 3 + d0) * kHin];
            v[t] = r0[x0] * w00 + r0[x0 + 1] * w01 +
                   r0[kHin + x0] * w10 + r0[kHin + x0 + 1] * w11;
            const float* r1 = &stage[(30 + c * 3 + d0) * kHin];
            u[t] = r1[x0] * w00 + r1[x0 + 1] * w01 +
                   r1[kHin + x0] * w10 + r1[kHin + x0 + 1] * w11;
            f[t] = stage[(60 + c) * kHin + sx];
        }
        xh0v2[j] = pk(v[0], v[1]);
        xh1v2[j] = pk(u[0], u[1]);
        xfv2[j]  = pk(f[0], f[1]);
    }

    // ---- xp loads -> packed half2 ----
    half2v xpv2[kP][5];
    {
        const float* b = xp + (size_t)(n * kP * kHD) * (kH * kH) + yc * kH + xc;
        #pragma unroll
        for (int p = 0; p < kP; ++p)
            #pragma unroll
            for (int j = 0; j < 5; ++j) {
                const float lo = b[(size_t)(p * kHD + 2 * j)     * (kH * kH)];
                const float hi = b[(size_t)(p * kHD + 2 * j + 1) * (kH * kH)];
                xpv2[p][j] = pk(lo, hi);
            }
    }

    // ---- attentions via fdot2 ----
    float attf[kP], atth[kP], dpa[kP];
    #pragma unroll
    for (int p = 0; p < kP; ++p) {
        float af = bfb[p], ah = bhb[p], ad = batt[p];
        #pragma unroll
        for (int j = 0; j < 5; ++j) {
            const half2v xh2 = (p < 4) ? xh0v2[j] : xh1v2[j];
            af = dot2(xfv2[j],    w2[WF2 + p * 10 + j],     af);
            af = dot2(xpv2[p][j], w2[WF2 + p * 10 + 5 + j], af);
            ah = dot2(xh2,        w2[WH2 + p * 10 + j],     ah);
            ah = dot2(xpv2[p][j], w2[WH2 + p * 10 + 5 + j], ah);
            ad = dot2(xpv2[p][j], w2[WATT2 + p * 5 + j],    ad);
        }
        attf[p] = sigm(af);
        atth[p] = sigm(ah);
        dpa[p]  = sigm(ad);
    }

    const size_t pixoff = (size_t)yc * kH + xc;
    #pragma unroll
    for (int p = 0; p < kP; ++p) {
        const float ap = (attf[p] + atth[p] + dpa[p]) * (1.0f / 3.0f);
        out_att[(size_t)(n * kP + p) * (kH * kH) + pixoff] = ap;
    }

    // ---- edge messages via fdot2 ----
    float xpp[kP][kHD];
    #pragma unroll
    for (int p = 0; p < kP; ++p)
        #pragma unroll
        for (int c = 0; c < kHD; ++c) xpp[p][c] = 0.0f;

    constexpr int EA[kNE] = {0, 1, 2, 1, 4};
    constexpr int EB[kNE] = {1, 2, 3, 4, 5};
    #pragma unroll
    for (int e = 0; e < kNE; ++e) {
        const int a = EA[e], b = EB[e];
        const float sa = 2.0f - dpa[a];
        const float sb = 2.0f - dpa[b];
        #pragma unroll
        for (int d = 0; d < kHD; ++d) {
            float t = 0.0f;
            #pragma unroll
            for (int j = 0; j < 5; ++j) {
                t = dot2(xpv2[a][j], w2[WDP2 + (e * kHD + d) * 10 + j],     t);
                t = dot2(xpv2[b][j], w2[WDP2 + (e * kHD + d) * 10 + 5 + j], t);
            }
            t = fmaxf(t, 0.0f);
            xpp[b][d] += t * sa;
            xpp[a][d] += t * sb;
        }
    }

    // ================== MFMA update ==================
    // wave geometry: wave wv covers 64 contiguous px of one row
    const int row_y = yA + (wv >> 1);
    const int wx0   = (wv & 1) << 6;
    const int r15   = lane & 15;
    const int g4    = lane >> 4;

    uint4* rowp = (uint4*)(&Abuf[wv][lane * 72]);
    rowp[5] = make_uint4(0, 0, 0, 0);   // zero A cols 40-63 (k-pad) once
    rowp[6] = make_uint4(0, 0, 0, 0);
    rowp[7] = make_uint4(0, 0, 0, 0);

    const _Float16* Aw = &Abuf[wv][0];

    #pragma unroll
    for (int p = 0; p < kP; ++p) {
        // B fragments (prepacked lane order): issue loads first
        const half8 b0 = *(const half8*)(wB + p * 1024 +       lane * 8);
        const half8 b1 = *(const half8*)(wB + p * 1024 + 512 + lane * 8);

        // build this lane's A row: [xpv | attf*xf | atth*xh | xpp] as f16
        const half2v sf = pk(attf[p], attf[p]);
        const half2v sh = pk(atth[p], atth[p]);
        unsigned wbuf[20];
        #pragma unroll
        for (int j = 0; j < 5; ++j) {
            const half2v xh2 = (p < 4) ? xh0v2[j] : xh1v2[j];
            wbuf[j]      = bc(xpv2[p][j]);
            wbuf[5 + j]  = bc(xfv2[j] * sf);
            wbuf[10 + j] = bc(xh2 * sh);
            wbuf[15 + j] = bc(pk(xpp[p][2 * j], xpp[p][2 * j + 1]));
        }
        rowp[0] = make_uint4(wbuf[0],  wbuf[1],  wbuf[2],  wbuf[3]);
        rowp[1] = make_uint4(wbuf[4],  wbuf[5],  wbuf[6],  wbuf[7]);
        rowp[2] = make_uint4(wbuf[8],  wbuf[9],  wbuf[10], wbuf[11]);
        rowp[3] = make_uint4(wbuf[12], wbuf[13], wbuf[14], wbuf[15]);
        rowp[4] = make_uint4(wbuf[16], wbuf[17], wbuf[18], wbuf[19]);

        // 4 row-groups of 16 px; K=64 (40 real) in 2 chunks
        #pragma unroll
        for (int rg = 0; rg < 4; ++rg) {
            const half8 a0 = *(const half8*)(Aw + (rg * 16 + r15) * 72 +      g4 * 8);
            const half8 a1 = *(const half8*)(Aw + (rg * 16 + r15) * 72 + 32 + g4 * 8);
            f32x4 acc = {0.0f, 0.0f, 0.0f, 0.0f};
            acc = __builtin_amdgcn_mfma_f32_16x16x32_f16(a0, b0, acc, 0, 0, 0);
            acc = __builtin_amdgcn_mfma_f32_16x16x32_f16(a1, b1, acc, 0, 0, 0);
            if (r15 < 10) {
                const size_t base =
                    ((size_t)((n * kP + p) * kHD + r15) << 14) +
                    (size_t)row_y * kH + wx0 + rg * 16 + g4 * 4;
                const float4 xpo = *(const float4*)(xp + base);
                float4 o;
                o.x = fmaxf(xpo.x + fmaxf(acc[0], 0.0f), 0.0f);
                o.y = fmaxf(xpo.y + fmaxf(acc[1], 0.0f), 0.0f);
                o.z = fmaxf(xpo.z + fmaxf(acc[2], 0.0f), 0.0f);
                o.w = fmaxf(xpo.w + fmaxf(acc[3], 0.0f), 0.0f);
                *(float4*)(out_xp + base) = o;
            }
        }
    }
}

extern "C" void kernel_launch(void* const* d_in, const int* in_sizes, int n_in,
                              void* d_out, int out_size, void* d_ws, size_t ws_size,
                              hipStream_t stream) {
    const float* xf   = (const float*)d_in[0];
    const float* xh0  = (const float*)d_in[1];
    const float* xh1  = (const float*)d_in[2];
    const float* xp   = (const float*)d_in[3];
    const float* Wf   = (const float*)d_in[4];
    const float* bfb  = (const float*)d_in[5];
    const float* Wh   = (const float*)d_in[6];
    const float* bhb  = (const float*)d_in[7];
    const float* Watt = (const float*)d_in[8];
    const float* batt = (const float*)d_in[9];
    const float* Wdp  = (const float*)d_in[10];
    const float* Wup  = (const float*)d_in[11];

    int N = out_size / ((kP * kHD + kP) * kH * kH);
    if (N <= 0) N = 32;
    const int npix = N * kH * kH;

    float* out_xp  = (float*)d_out;
    float* out_att = out_xp + (size_t)N * kP * kHD * kH * kH;
    half2v*   w2  = (half2v*)d_ws;
    _Float16* wsB = (_Float16*)((char*)d_ws + kBOff);

    prepack_weights<<<(NPAIR + 255) / 256, 256, 0, stream>>>(
        Wf, Wh, Watt, Wdp, w2);
    prepack_mfma_b<<<(6144 + 255) / 256, 256, 0, stream>>>(Wup, wsB);

    const int block = 256;
    const int grid = npix / block;
    Part_Graph_51539607552364_kernel<<<grid, block, 0, stream>>>(
        xf, xh0, xh1, xp, w2, wsB, bfb, bhb, batt, out_xp, out_att);
}

// Round 16
// 88.705 us; speedup vs baseline: 1.2806x; 1.2806x over previous
//
#include <hip/hip_runtime.h>
#include <hip/hip_bf16.h>

typedef _Float16 half2v __attribute__((ext_vector_type(2)));
typedef _Float16 half8  __attribute__((ext_vector_type(8)));
typedef float    f32x4  __attribute__((ext_vector_type(4)));

constexpr int kHD  = 10;
constexpr int kP   = 6;
constexpr int kNE  = 5;
constexpr int kH   = 128;
constexpr int kHin = 64;
constexpr int kSeg = 70;    // 60 xh row-segments + 10 xf row-segments

// packed-weight layout in d_ws (half2 pairs) -- attn + edge phases
constexpr int WF2  = 0;     // 60  : Wf  [p][20]
constexpr int WH2  = 60;    // 60  : Wh  [p][20]
constexpr int WATT2= 120;   // 30  : Watt[p][10]
constexpr int WDP2 = 150;   // 500 : Wdp [e][10][20]
constexpr int NPAIR= 650;
// MFMA B-fragments at byte offset 8192 in d_ws
constexpr int kBOff = 8192;

__device__ __forceinline__ float sigm(float v) {
    return 1.0f / (1.0f + __expf(-v));
}
__device__ __forceinline__ half2v pk(float a, float b) {
    half2v h; h[0] = (_Float16)a; h[1] = (_Float16)b; return h;
}
__device__ __forceinline__ unsigned bc(half2v h) {
    union { half2v h; unsigned u; } x; x.h = h; return x.u;
}
__device__ __forceinline__ float dot2(half2v a, half2v b, float c) {
    return __builtin_amdgcn_fdot2(a, b, c, false);
}

__global__ __launch_bounds__(256)
void prepack_weights(const float* __restrict__ Wf,  const float* __restrict__ Wh,
                     const float* __restrict__ Watt, const float* __restrict__ Wdp,
                     half2v* __restrict__ out)
{
    const int i = blockIdx.x * 256 + threadIdx.x;
    if (i >= NPAIR) return;
    const float* src; int k;
    if      (i < WH2)   { src = Wf;   k = i; }
    else if (i < WATT2) { src = Wh;   k = i - WH2; }
    else if (i < WDP2)  { src = Watt; k = i - WATT2; }
    else                { src = Wdp;  k = i - WDP2; }
    out[i] = pk(src[2 * k], src[2 * k + 1]);
}

// B-fragment prepack for mfma_f32_16x16x32_f16: lane l supplies
// B[k = q*32 + (l>>4)*8 + e][col = l&15], zero outside (k<40, col<10).
__global__ __launch_bounds__(256)
void prepack_mfma_b(const float* __restrict__ Wup, _Float16* __restrict__ outB)
{
    const int t = blockIdx.x * 256 + threadIdx.x;
    if (t >= 6144) return;
    const int e = t & 7;
    const int l = (t >> 3) & 63;
    const int q = (t >> 9) & 1;
    const int p = t >> 10;
    const int k = q * 32 + (l >> 4) * 8 + e;
    const int col = l & 15;
    _Float16 v = (_Float16)0.0f;
    if (k < 40 && col < 10) v = (_Float16)Wup[(p * kHD + col) * 40 + k];
    outB[t] = v;
}

// MFMA v2: 128B A-rows (8 chunks = K=64 exactly) with XOR chunk swizzle
// (chunk' = chunk ^ (row&7)) on write AND read -> 8-phase-optimal LDS.
// Epilogue reads f16 xp back from the A-buffer (no global xp reload).
__global__ __launch_bounds__(256, 2)
void Part_Graph_51539607552364_kernel(
    const float* __restrict__ xf,  const float* __restrict__ xh0,
    const float* __restrict__ xh1, const float* __restrict__ xp,
    const half2v* __restrict__ w2, const _Float16* __restrict__ wB,
    const float* __restrict__ bfb, const float* __restrict__ bhb,
    const float* __restrict__ batt,
    float* __restrict__ out_xp,
    float* __restrict__ out_att)
{
    __shared__ float stage[kSeg * kHin];                 // 17920 B
    __shared__ __align__(16) _Float16 Abuf[4][64 * 64];  // 32768 B (tot 50688)

    const int bid = blockIdx.x;
    const int n   = bid >> 6;
    const int R   = bid & 63;
    const int yA  = R * 2;

    const float scale = 63.0f / 127.0f;
    int ry0 = (int)((float)yA * scale);
    ry0 = ry0 > (kHin - 2) ? (kHin - 2) : ry0;

    const int wv   = threadIdx.x >> 6;
    const int lane = threadIdx.x & 63;

    // ---- cooperative staging (R13 verbatim) ----
    for (int s = wv; s < kSeg; s += 4) {
        const float* src;
        if (s < 60) {
            const int map = s / 30, rem = s % 30;
            const int ch = rem / 3, r3 = rem % 3;
            int srow = ry0 + r3;
            srow = srow > (kHin - 1) ? (kHin - 1) : srow;
            src = (map ? xh1 : xh0) +
                  ((size_t)(n * kHD + ch) * kHin + srow) * kHin;
        } else {
            const int ch = s - 60;
            src = xf + ((size_t)(n * kHD + ch) * kHin + R) * kHin;
        }
        stage[s * kHin + lane] = src[lane];
    }
    __syncthreads();

    const int ly = threadIdx.x >> 7;
    const int xc = threadIdx.x & (kH - 1);
    const int yc = yA + ly;

    // ---- bilinear coords ----
    const float py = (float)yc * scale;
    int y0 = (int)py; y0 = y0 > (kHin - 2) ? (kHin - 2) : y0;
    const float fy = py - (float)y0;
    const int d0 = y0 - ry0;
    const float pxf_ = (float)xc * scale;
    int x0 = (int)pxf_; x0 = x0 > (kHin - 2) ? (kHin - 2) : x0;
    const float fx = pxf_ - (float)x0;
    const float w00 = (1.0f - fy) * (1.0f - fx);
    const float w01 = (1.0f - fy) * fx;
    const float w10 = fy * (1.0f - fx);
    const float w11 = fy * fx;

    // ---- windows from LDS -> packed half2 ----
    half2v xh0v2[5], xh1v2[5], xfv2[5];
    const int sx = xc >> 1;
    #pragma unroll
    for (int j = 0; j < 5; ++j) {
        float v[2], u[2], f[2];
        #pragma unroll
        for (int t = 0; t < 2; ++t) {
            const int c = 2 * j + t;
            const float* r0 = &stage[(c * 3 + d0) * kHin];
            v[t] = r0[x0] * w00 + r0[x0 + 1] * w01 +
                   r0[kHin + x0] * w10 + r0[kHin + x0 + 1] * w11;
            const float* r1 = &stage[(30 + c * 3 + d0) * kHin];
            u[t] = r1[x0] * w00 + r1[x0 + 1] * w01 +
                   r1[kHin + x0] * w10 + r1[kHin + x0 + 1] * w11;
            f[t] = stage[(60 + c) * kHin + sx];
        }
        xh0v2[j] = pk(v[0], v[1]);
        xh1v2[j] = pk(u[0], u[1]);
        xfv2[j]  = pk(f[0], f[1]);
    }

    // ---- xp loads -> packed half2 ----
    half2v xpv2[kP][5];
    {
        const float* b = xp + (size_t)(n * kP * kHD) * (kH * kH) + yc * kH + xc;
        #pragma unroll
        for (int p = 0; p < kP; ++p)
            #pragma unroll
            for (int j = 0; j < 5; ++j) {
                const float lo = b[(size_t)(p * kHD + 2 * j)     * (kH * kH)];
                const float hi = b[(size_t)(p * kHD + 2 * j + 1) * (kH * kH)];
                xpv2[p][j] = pk(lo, hi);
            }
    }

    // ---- attentions via fdot2 ----
    float attf[kP], atth[kP], dpa[kP];
    #pragma unroll
    for (int p = 0; p < kP; ++p) {
        float af = bfb[p], ah = bhb[p], ad = batt[p];
        #pragma unroll
        for (int j = 0; j < 5; ++j) {
            const half2v xh2 = (p < 4) ? xh0v2[j] : xh1v2[j];
            af = dot2(xfv2[j],    w2[WF2 + p * 10 + j],     af);
            af = dot2(xpv2[p][j], w2[WF2 + p * 10 + 5 + j], af);
            ah = dot2(xh2,        w2[WH2 + p * 10 + j],     ah);
            ah = dot2(xpv2[p][j], w2[WH2 + p * 10 + 5 + j], ah);
            ad = dot2(xpv2[p][j], w2[WATT2 + p * 5 + j],    ad);
        }
        attf[p] = sigm(af);
        atth[p] = sigm(ah);
        dpa[p]  = sigm(ad);
    }

    const size_t pixoff = (size_t)yc * kH + xc;
    #pragma unroll
    for (int p = 0; p < kP; ++p) {
        const float ap = (attf[p] + atth[p] + dpa[p]) * (1.0f / 3.0f);
        out_att[(size_t)(n * kP + p) * (kH * kH) + pixoff] = ap;
    }

    // ---- edge messages via fdot2, pack xpp -> half2 immediately ----
    float xpp[kP][kHD];
    #pragma unroll
    for (int p = 0; p < kP; ++p)
        #pragma unroll
        for (int c = 0; c < kHD; ++c) xpp[p][c] = 0.0f;

    constexpr int EA[kNE] = {0, 1, 2, 1, 4};
    constexpr int EB[kNE] = {1, 2, 3, 4, 5};
    #pragma unroll
    for (int e = 0; e < kNE; ++e) {
        const int a = EA[e], b = EB[e];
        const float sa = 2.0f - dpa[a];
        const float sb = 2.0f - dpa[b];
        #pragma unroll
        for (int d = 0; d < kHD; ++d) {
            float t = 0.0f;
            #pragma unroll
            for (int j = 0; j < 5; ++j) {
                t = dot2(xpv2[a][j], w2[WDP2 + (e * kHD + d) * 10 + j],     t);
                t = dot2(xpv2[b][j], w2[WDP2 + (e * kHD + d) * 10 + 5 + j], t);
            }
            t = fmaxf(t, 0.0f);
            xpp[b][d] += t * sa;
            xpp[a][d] += t * sb;
        }
    }
    half2v xpp2[kP][5];
    #pragma unroll
    for (int p = 0; p < kP; ++p)
        #pragma unroll
        for (int j = 0; j < 5; ++j)
            xpp2[p][j] = pk(xpp[p][2 * j], xpp[p][2 * j + 1]);

    // ================== MFMA update (v2) ==================
    const int row_y = yA + (wv >> 1);
    const int wx0   = (wv & 1) << 6;
    const int r15   = lane & 15;
    const int g4    = lane >> 4;

    char* Ab = (char*)&Abuf[wv][0];
    char* rb = Ab + lane * 128;

    // zero k=40..63 chunks (swizzled positions), static across parts
    const uint4 z4 = make_uint4(0, 0, 0, 0);
    *(uint4*)(rb + ((5 ^ (lane & 7)) << 4)) = z4;
    *(uint4*)(rb + ((6 ^ (lane & 7)) << 4)) = z4;
    *(uint4*)(rb + ((7 ^ (lane & 7)) << 4)) = z4;

    #pragma unroll
    for (int p = 0; p < kP; ++p) {
        // B fragments (prepacked lane order)
        const half8 b0 = *(const half8*)(wB + p * 1024 +       lane * 8);
        const half8 b1 = *(const half8*)(wB + p * 1024 + 512 + lane * 8);

        // build this lane's A row: [xpv | attf*xf | atth*xh | xpp] as f16
        const half2v sf = pk(attf[p], attf[p]);
        const half2v sh = pk(atth[p], atth[p]);
        unsigned wbuf[20];
        #pragma unroll
        for (int j = 0; j < 5; ++j) {
            const half2v xh2 = (p < 4) ? xh0v2[j] : xh1v2[j];
            wbuf[j]      = bc(xpv2[p][j]);
            wbuf[5 + j]  = bc(xfv2[j] * sf);
            wbuf[10 + j] = bc(xh2 * sh);
            wbuf[15 + j] = bc(xpp2[p][j]);
        }
        *(uint4*)(rb + ((0 ^ (lane & 7)) << 4)) =
            make_uint4(wbuf[0],  wbuf[1],  wbuf[2],  wbuf[3]);
        *(uint4*)(rb + ((1 ^ (lane & 7)) << 4)) =
            make_uint4(wbuf[4],  wbuf[5],  wbuf[6],  wbuf[7]);
        *(uint4*)(rb + ((2 ^ (lane & 7)) << 4)) =
            make_uint4(wbuf[8],  wbuf[9],  wbuf[10], wbuf[11]);
        *(uint4*)(rb + ((3 ^ (lane & 7)) << 4)) =
            make_uint4(wbuf[12], wbuf[13], wbuf[14], wbuf[15]);
        *(uint4*)(rb + ((4 ^ (lane & 7)) << 4)) =
            make_uint4(wbuf[16], wbuf[17], wbuf[18], wbuf[19]);

        // 4 row-groups of 16 px; K=64 (40 real) in 2 chunks
        #pragma unroll
        for (int rg = 0; rg < 4; ++rg) {
            const int row = rg * 16 + r15;
            const half8 a0 =
                *(const half8*)(Ab + row * 128 + (((0 + g4) ^ (row & 7)) << 4));
            const half8 a1 =
                *(const half8*)(Ab + row * 128 + (((4 + g4) ^ (row & 7)) << 4));
            f32x4 acc = {0.0f, 0.0f, 0.0f, 0.0f};
            acc = __builtin_amdgcn_mfma_f32_16x16x32_f16(a0, b0, acc, 0, 0, 0);
            acc = __builtin_amdgcn_mfma_f32_16x16x32_f16(a1, b1, acc, 0, 0, 0);
            if (r15 < 10) {
                // read back f16 xp from A-buffer chunk (k = channel r15)
                const int chnk = r15 >> 3, hoff = (r15 & 7) * 2;
                float o[4];
                #pragma unroll
                for (int j = 0; j < 4; ++j) {
                    const int px = rg * 16 + g4 * 4 + j;
                    const _Float16 xh_ = *(const _Float16*)(
                        Ab + px * 128 + ((chnk ^ (px & 7)) << 4) + hoff);
                    o[j] = fmaxf((float)xh_ + fmaxf(acc[j], 0.0f), 0.0f);
                }
                const size_t base =
                    ((size_t)((n * kP + p) * kHD + r15) << 14) +
                    (size_t)row_y * kH + wx0 + rg * 16 + g4 * 4;
                *(float4*)(out_xp + base) = make_float4(o[0], o[1], o[2], o[3]);
            }
        }
    }
}

extern "C" void kernel_launch(void* const* d_in, const int* in_sizes, int n_in,
                              void* d_out, int out_size, void* d_ws, size_t ws_size,
                              hipStream_t stream) {
    const float* xf   = (const float*)d_in[0];
    const float* xh0  = (const float*)d_in[1];
    const float* xh1  = (const float*)d_in[2];
    const float* xp   = (const float*)d_in[3];
    const float* Wf   = (const float*)d_in[4];
    const float* bfb  = (const float*)d_in[5];
    const float* Wh   = (const float*)d_in[6];
    const float* bhb  = (const float*)d_in[7];
    const float* Watt = (const float*)d_in[8];
    const float* batt = (const float*)d_in[9];
    const float* Wdp  = (const float*)d_in[10];
    const float* Wup  = (const float*)d_in[11];

    int N = out_size / ((kP * kHD + kP) * kH * kH);
    if (N <= 0) N = 32;
    const int npix = N * kH * kH;

    float* out_xp  = (float*)d_out;
    float* out_att = out_xp + (size_t)N * kP * kHD * kH * kH;
    half2v*   w2  = (half2v*)d_ws;
    _Float16* wsB = (_Float16*)((char*)d_ws + kBOff);

    prepack_weights<<<(NPAIR + 255) / 256, 256, 0, stream>>>(
        Wf, Wh, Watt, Wdp, w2);
    prepack_mfma_b<<<(6144 + 255) / 256, 256, 0, stream>>>(Wup, wsB);

    const int block = 256;
    const int grid = npix / block;
    Part_Graph_51539607552364_kernel<<<grid, block, 0, stream>>>(
        xf, xh0, xh1, xp, w2, wsB, bfb, bhb, batt, out_xp, out_att);
}